// Round 17
// baseline (301.952 us; speedup 1.0000x reference)
//
#include <hip/hip_runtime.h>
#include <math.h>

#define TPB 256
#define NPTS 1024

template<int P, int Q, int R>
__device__ __forceinline__ void jrot(float a[3][3], float V[3][3]) {
  float apq = a[P][Q];
  if (fabsf(apq) < 1e-30f) return;
  float theta = (a[Q][Q] - a[P][P]) / (2.0f * apq);
  float t = copysignf(1.0f, theta) / (fabsf(theta) + sqrtf(theta * theta + 1.0f));
  float c = 1.0f / sqrtf(t * t + 1.0f);
  float s = t * c;
  float app = a[P][P], aqq = a[Q][Q];
  a[P][P] = app - t * apq;
  a[Q][Q] = aqq + t * apq;
  a[P][Q] = 0.0f; a[Q][P] = 0.0f;
  float arp = a[R][P], arq = a[R][Q];
  a[R][P] = c * arp - s * arq; a[P][R] = a[R][P];
  a[R][Q] = s * arp + c * arq; a[Q][R] = a[R][Q];
#pragma unroll
  for (int i = 0; i < 3; ++i) {
    float vip = V[i][P], viq = V[i][Q];
    V[i][P] = c * vip - s * viq;
    V[i][Q] = s * vip + c * viq;
  }
}

#define CSWAP(I, J)                                                        \
  if (ev[I] < ev[J]) {                                                     \
    float e_ = ev[I]; ev[I] = ev[J]; ev[J] = e_;                           \
    _Pragma("unroll")                                                      \
    for (int r2_ = 0; r2_ < 3; ++r2_) {                                    \
      float v_ = V[r2_][I]; V[r2_][I] = V[r2_][J]; V[r2_][J] = v_;         \
    }                                                                      \
  }

__device__ __forceinline__ void svd_tail_write(const float r[16], float* o) {
  const float S = r[0];
  const float inv = 1.0f / (S + 1e-5f);
  const float sc[3] = {r[1] * inv, r[2] * inv, r[3] * inv};
  const float tc[3] = {r[4] * inv, r[5] * inv, r[6] * inv};
  const float f = 2.0f - S * inv;

  float H[3][3];
#pragma unroll
  for (int c = 0; c < 3; ++c)
#pragma unroll
    for (int d = 0; d < 3; ++d)
      H[c][d] = r[7 + 3 * c + d] * inv - sc[c] * tc[d] * f;

  float Bm[3][3];
#pragma unroll
  for (int i = 0; i < 3; ++i)
#pragma unroll
    for (int j = 0; j < 3; ++j)
      Bm[i][j] = H[0][i] * H[0][j] + H[1][i] * H[1][j] + H[2][i] * H[2][j];

  float V[3][3] = {{1, 0, 0}, {0, 1, 0}, {0, 0, 1}};
  for (int sweep = 0; sweep < 8; ++sweep) {
    jrot<0, 1, 2>(Bm, V);
    jrot<0, 2, 1>(Bm, V);
    jrot<1, 2, 0>(Bm, V);
  }
  float ev[3] = {Bm[0][0], Bm[1][1], Bm[2][2]};
  CSWAP(0, 1)
  CSWAP(1, 2)
  CSWAP(0, 1)

  float U[3][3];
  float w0[3], w1[3];
#pragma unroll
  for (int i = 0; i < 3; ++i)
    w0[i] = H[i][0] * V[0][0] + H[i][1] * V[1][0] + H[i][2] * V[2][0];
  float n0 = sqrtf(w0[0] * w0[0] + w0[1] * w0[1] + w0[2] * w0[2]);
  float in0 = (n0 > 1e-20f) ? 1.0f / n0 : 0.0f;
#pragma unroll
  for (int i = 0; i < 3; ++i) U[i][0] = w0[i] * in0;

#pragma unroll
  for (int i = 0; i < 3; ++i)
    w1[i] = H[i][0] * V[0][1] + H[i][1] * V[1][1] + H[i][2] * V[2][1];
  float d01 = U[0][0] * w1[0] + U[1][0] * w1[1] + U[2][0] * w1[2];
#pragma unroll
  for (int i = 0; i < 3; ++i) w1[i] -= d01 * U[i][0];
  float n1 = sqrtf(w1[0] * w1[0] + w1[1] * w1[1] + w1[2] * w1[2]);
  float in1 = (n1 > 1e-20f) ? 1.0f / n1 : 0.0f;
#pragma unroll
  for (int i = 0; i < 3; ++i) U[i][1] = w1[i] * in1;

  U[0][2] = U[1][0] * U[2][1] - U[2][0] * U[1][1];
  U[1][2] = U[2][0] * U[0][1] - U[0][0] * U[2][1];
  U[2][2] = U[0][0] * U[1][1] - U[1][0] * U[0][1];

  float detV = V[0][0] * (V[1][1] * V[2][2] - V[1][2] * V[2][1]) -
               V[0][1] * (V[1][0] * V[2][2] - V[1][2] * V[2][0]) +
               V[0][2] * (V[1][0] * V[2][1] - V[1][1] * V[2][0]);
  float s3 = (detV >= 0.0f) ? 1.0f : -1.0f;

  float R[3][3];
#pragma unroll
  for (int i = 0; i < 3; ++i)
#pragma unroll
    for (int j = 0; j < 3; ++j)
      R[i][j] = V[i][0] * U[j][0] + V[i][1] * U[j][1] + s3 * V[i][2] * U[j][2];

  float tr[3];
#pragma unroll
  for (int i = 0; i < 3; ++i)
    tr[i] = tc[i] - (R[i][0] * sc[0] + R[i][1] * sc[1] + R[i][2] * sc[2]);

  float4* o4 = (float4*)o;
  o4[0] = make_float4(R[0][0], R[0][1], R[0][2], tr[0]);
  o4[1] = make_float4(R[1][0], R[1][1], R[1][2], tr[1]);
  o4[2] = make_float4(R[2][0], R[2][1], R[2][2], tr[2]);
  o4[3] = make_float4(0.0f, 0.0f, 0.0f, 1.0f);
}

// Compile-time float4-array component access (folds to a register under
// #pragma unroll; avoids pointer-casting locals which can force scratch).
#define F4C(A, I)                                                    \
  (((I) & 3) == 0   ? A[(I) >> 2].x                                  \
   : ((I) & 3) == 1 ? A[(I) >> 2].y                                  \
   : ((I) & 3) == 2 ? A[(I) >> 2].z                                  \
                    : A[(I) >> 2].w)

// One WAVE per batch, zero barriers, zero LDS. Each lane owns 16
// consecutive points: 12+12+4 = 28 independent float4 loads issued
// back-to-back (28 KB in flight per wave; lane-contiguous 192B runs, so
// unique-cacheline count equals the ideal). Reduction is pure-register
// (6-level butterfly). Every prior structure (R2/R7/R8/R9/R12: 85-112us,
// all ~2.5 TB/s) had waves issuing <=7 loads between barrier/waitcnt
// phases -> ~4KB/CU actually in flight. This maximizes concurrency and
// removes all inter-wave coupling.
__global__ __launch_bounds__(TPB) void wproc_wave(
    const float* __restrict__ src, const float* __restrict__ tgt,
    const float* __restrict__ wts, float* __restrict__ ws, int nbat) {
  const int wid = blockIdx.x * (TPB / 64) + (threadIdx.x >> 6);  // batch
  const int l = threadIdx.x & 63;
  if (wid >= nbat) return;

  const float4* gs = (const float4*)src + (size_t)wid * 768 + l * 12;
  const float4* gt = (const float4*)tgt + (size_t)wid * 768 + l * 12;
  const float4* gw = (const float4*)wts + (size_t)wid * 256 + l * 4;

  float4 s[12], u[12], w[4];
#pragma unroll
  for (int i = 0; i < 12; ++i) s[i] = gs[i];
#pragma unroll
  for (int i = 0; i < 12; ++i) u[i] = gt[i];
#pragma unroll
  for (int i = 0; i < 4; ++i) w[i] = gw[i];

  // acc: [0]=Sw, [1..3]=Σw*src, [4..6]=Σw*tgt, [7..15]=Σw*src⊗tgt
  float acc[16];
#pragma unroll
  for (int k = 0; k < 16; ++k) acc[k] = 0.0f;

#pragma unroll
  for (int j = 0; j < 16; ++j) {
    const float wv = fmaxf(F4C(w, j), 0.0f);  // WEIGHT_THRESH = 0.0
    const float sx = F4C(s, 3 * j + 0), sy = F4C(s, 3 * j + 1),
                sz = F4C(s, 3 * j + 2);
    const float tx = F4C(u, 3 * j + 0), ty = F4C(u, 3 * j + 1),
                tz = F4C(u, 3 * j + 2);
    const float wsx = wv * sx, wsy = wv * sy, wsz = wv * sz;
    acc[0] += wv;
    acc[1] += wsx;      acc[2] += wsy;      acc[3] += wsz;
    acc[4] += wv * tx;  acc[5] += wv * ty;  acc[6] += wv * tz;
    acc[7]  += wsx * tx; acc[8]  += wsx * ty; acc[9]  += wsx * tz;
    acc[10] += wsy * tx; acc[11] += wsy * ty; acc[12] += wsy * tz;
    acc[13] += wsz * tx; acc[14] += wsz * ty; acc[15] += wsz * tz;
  }

  // Full wave butterfly: acc[k] summed across 64 lanes (lane 0 final).
#pragma unroll
  for (int off = 32; off >= 1; off >>= 1) {
#pragma unroll
    for (int k = 0; k < 16; ++k) acc[k] += __shfl_down(acc[k], off, 64);
  }

  if (l == 0) {
    float4* o = (float4*)(ws + (size_t)wid * 16);
    o[0] = make_float4(acc[0], acc[1], acc[2], acc[3]);
    o[1] = make_float4(acc[4], acc[5], acc[6], acc[7]);
    o[2] = make_float4(acc[8], acc[9], acc[10], acc[11]);
    o[3] = make_float4(acc[12], acc[13], acc[14], acc[15]);
  }
}

// One thread per batch: fully parallel 3x3 SVD + transform assembly.
__global__ __launch_bounds__(TPB) void wproc_svd(
    const float* __restrict__ ws, float* __restrict__ out, int B) {
  const int i = blockIdx.x * TPB + threadIdx.x;
  if (i >= B) return;
  const float4* p = (const float4*)(ws + (size_t)i * 16);
  const float4 a = p[0], bq = p[1], c = p[2], d = p[3];
  const float r[16] = {a.x,  a.y,  a.z,  a.w,  bq.x, bq.y, bq.z, bq.w,
                       c.x,  c.y,  c.z,  c.w,  d.x,  d.y,  d.z,  d.w};
  svd_tail_write(r, out + (size_t)i * 16);
}

// Fallback (ws too small): fused single kernel (R9-proven, absmax 3.9e-3).
__global__ __launch_bounds__(TPB) void wproc_fused(
    const float* __restrict__ src, const float* __restrict__ tgt,
    const float* __restrict__ wts, float* __restrict__ out) {
  const int b = blockIdx.x;
  const int t = threadIdx.x;
  const int lane = t & 63, wave = t >> 6;

  __shared__ float4 sh_src[NPTS * 3 / 4];
  __shared__ float4 sh_tgt[NPTS * 3 / 4];
  __shared__ float sh_fin[4][17];
  __shared__ float sh_r[16];
  float(*sh_part)[20] = (float(*)[20])sh_src;

  const float4* g_src = (const float4*)(src + (size_t)b * (NPTS * 3));
  const float4* g_tgt = (const float4*)(tgt + (size_t)b * (NPTS * 3));
  const float* g_w = wts + (size_t)b * NPTS;

#pragma unroll
  for (int i = 0; i < 3; ++i) {
    sh_src[t + i * TPB] = g_src[t + i * TPB];
    sh_tgt[t + i * TPB] = g_tgt[t + i * TPB];
  }
  const float wv0 = g_w[t], wv1 = g_w[t + 256], wv2 = g_w[t + 512],
              wv3 = g_w[t + 768];
  __syncthreads();

  const float* ss = (const float*)sh_src;
  const float* st = (const float*)sh_tgt;

  float acc[16];
#pragma unroll
  for (int k = 0; k < 16; ++k) acc[k] = 0.0f;

  const float wreg[4] = {wv0, wv1, wv2, wv3};
#pragma unroll
  for (int i = 0; i < 4; ++i) {
    const int p = t + i * TPB;
    float wv = fmaxf(wreg[i], 0.0f);
    const float sx = ss[3 * p + 0], sy = ss[3 * p + 1], sz = ss[3 * p + 2];
    const float tx = st[3 * p + 0], ty = st[3 * p + 1], tz = st[3 * p + 2];
    const float wsx = wv * sx, wsy = wv * sy, wsz = wv * sz;
    acc[0] += wv;
    acc[1] += wsx;      acc[2] += wsy;      acc[3] += wsz;
    acc[4] += wv * tx;  acc[5] += wv * ty;  acc[6] += wv * tz;
    acc[7]  += wsx * tx; acc[8]  += wsx * ty; acc[9]  += wsx * tz;
    acc[10] += wsy * tx; acc[11] += wsy * ty; acc[12] += wsy * tz;
    acc[13] += wsz * tx; acc[14] += wsz * ty; acc[15] += wsz * tz;
  }

#pragma unroll
  for (int k = 0; k < 16; ++k) acc[k] += __shfl_down(acc[k], 32, 64);
#pragma unroll
  for (int k = 0; k < 16; ++k) acc[k] += __shfl_down(acc[k], 16, 64);

  __syncthreads();

  if (lane < 16) {
    float4* pr = (float4*)&sh_part[wave * 16 + lane][0];
    pr[0] = make_float4(acc[0], acc[1], acc[2], acc[3]);
    pr[1] = make_float4(acc[4], acc[5], acc[6], acc[7]);
    pr[2] = make_float4(acc[8], acc[9], acc[10], acc[11]);
    pr[3] = make_float4(acc[12], acc[13], acc[14], acc[15]);
  }
  __syncthreads();

  if (t < 64) {
    const int k = t & 15, g = t >> 4;
    float s = 0.0f;
#pragma unroll
    for (int jj = 0; jj < 16; ++jj) s += sh_part[g * 16 + jj][k];
    sh_fin[g][k] = s;
  }
  __syncthreads();

  if (t < 16)
    sh_r[t] = sh_fin[0][t] + sh_fin[1][t] + sh_fin[2][t] + sh_fin[3][t];
  __syncthreads();

  if (t != 0) return;
  float r[16];
#pragma unroll
  for (int k = 0; k < 16; ++k) r[k] = sh_r[k];
  svd_tail_write(r, out + (size_t)b * 16);
}

extern "C" void kernel_launch(void* const* d_in, const int* in_sizes, int n_in,
                              void* d_out, int out_size, void* d_ws, size_t ws_size,
                              hipStream_t stream) {
  const float* src = (const float*)d_in[0];
  const float* tgt = (const float*)d_in[1];
  const float* wts = (const float*)d_in[2];
  float* out = (float*)d_out;
  const int B = in_sizes[0] / (NPTS * 3);
  const size_t need = (size_t)B * 16 * sizeof(float);
  if (ws_size >= need) {
    const int wavesPerBlock = TPB / 64;
    const int grid = (B + wavesPerBlock - 1) / wavesPerBlock;  // 2048
    wproc_wave<<<dim3(grid), dim3(TPB), 0, stream>>>(src, tgt, wts,
                                                     (float*)d_ws, B);
    wproc_svd<<<dim3((B + TPB - 1) / TPB), dim3(TPB), 0, stream>>>(
        (const float*)d_ws, out, B);
  } else {
    wproc_fused<<<dim3(B), dim3(TPB), 0, stream>>>(src, tgt, wts, out);
  }
}